// Round 1
// baseline (1903.395 us; speedup 1.0000x reference)
//
#include <hip/hip_runtime.h>

typedef _Float16 f16;
typedef _Float16 f16x8 __attribute__((ext_vector_type(8)));
typedef float f32x16 __attribute__((ext_vector_type(16)));

#define THREADS 512
#define MTILE   128
#define NBLK    256

// LDS layout (bytes)
#define AH_OFF   0          // f16 [128][256] swizzled hi, 65536 B
#define AL_OFF   65536      // f16 [128][256] swizzled lo, 65536 B
#define H2_OFF   0          // f32 [128][256] swizzled (aliases Ah/Al)
#define XS_OFF   131072     // f32 [128][3], 1536 B
#define W1P_OFF  132608     // float4 [256] = {w1[h][0..2], b1[h]}, 4096 B
#define B2_OFF   136704     // f32 [256], 1024 B
#define W3_OFF   137728     // f32 [3][256], 3072 B
#define B3_OFF   140800     // f32 [3] + pad
#define LDS_BYTES 140816

__global__ __launch_bounds__(THREADS, 2)
void fused_mlp_parity(const float* __restrict__ x,
                      const float* __restrict__ w1,
                      const float* __restrict__ b1,
                      const float* __restrict__ w2,
                      const float* __restrict__ b2,
                      const float* __restrict__ w3,
                      const float* __restrict__ b3,
                      float* __restrict__ out, int Bsz) {
  __shared__ __align__(128) unsigned char lds[LDS_BYTES];
  const int tid  = threadIdx.x;
  const int lane = tid & 63;
  const int wave = tid >> 6;

  float*  xs  = (float*) (lds + XS_OFF);
  float4* w1p = (float4*)(lds + W1P_OFF);
  float*  b2s = (float*) (lds + B2_OFF);
  float*  w3s = (float*) (lds + W3_OFF);
  float*  b3s = (float*) (lds + B3_OFF);

  // ---- one-time staging of small weights ----
  for (int i = tid; i < 256; i += THREADS) {
    float4 v;
    v.x = w1[i*3+0]; v.y = w1[i*3+1]; v.z = w1[i*3+2]; v.w = b1[i];
    w1p[i] = v;
  }
  for (int i = tid; i < 256; i += THREADS) b2s[i] = b2[i];
  for (int i = tid; i < 768; i += THREADS) w3s[i] = w3[i];
  if (tid < 3) b3s[tid] = b3[tid];

  // ---- B operand (w2^T slice per wave), register-resident f16 hi/lo ----
  // B[k][n] = w2[n][k]; lane holds col n = nb+(lane&31), k = 16*ks + 8*(lane>>5)+i
  const int arow  = lane & 31;
  const int khalf = (lane >> 5) << 3;           // 0 or 8 elements
  const int nb    = wave << 5;                  // 32-col slice per wave
  f16x8 Bh[16], Bl[16];
#pragma unroll
  for (int ks = 0; ks < 16; ++ks) {
    const float* src = w2 + (nb + arow) * 256 + ks * 16 + khalf;
    float4 u0 = *(const float4*)(src);
    float4 u1 = *(const float4*)(src + 4);
    float vv[8] = {u0.x,u0.y,u0.z,u0.w,u1.x,u1.y,u1.z,u1.w};
    f16x8 bh, bl;
#pragma unroll
    for (int i = 0; i < 8; ++i) {
      float v = vv[i];
      f16 h = (f16)v;
      bh[i] = h;
      bl[i] = (f16)((v - (float)h) * 2048.0f);   // lo scaled by 2^11
    }
    Bh[ks] = bh; Bl[ks] = bl;
  }

  const int ntiles  = Bsz / MTILE;
  const size_t outL = (size_t)Bsz * 2;
  const uint32_t aswz  = (uint32_t)arow << 4;    // 5-bit XOR swizzle key
  const uint32_t koffb = (uint32_t)khalf << 1;   // 0 or 16 bytes

  for (int tile = blockIdx.x; tile < ntiles; tile += gridDim.x) {
    const size_t base = (size_t)tile * MTILE;

    // ---- phase A: stage x tile (also fences prev tile's phase E vs next B) ----
    if (tid < MTILE*3) xs[tid] = x[base*3 + tid];
    __syncthreads();

    // ---- phase B: h1 = relu(x@w1^T + b1) fp32, split -> f16 hi/lo in LDS ----
    {
      const int hb = tid & 31;                   // h block: h0 = 8*hb
      const int rg = tid >> 5;                   // 16 row-groups of 8 rows
      const uint32_t hbyte = (uint32_t)hb << 4;  // h0*2 bytes
      float4 wv[8];
#pragma unroll
      for (int i = 0; i < 8; ++i) wv[i] = w1p[hb*8 + i];
#pragma unroll
      for (int rr = 0; rr < 8; ++rr) {
        const int r = rg*8 + rr;
        const float x0 = xs[r*3+0], x1 = xs[r*3+1], x2 = xs[r*3+2];
        f16x8 ah, al;
#pragma unroll
        for (int i = 0; i < 8; ++i) {
          float v = fmaf(x2, wv[i].z, fmaf(x1, wv[i].y, fmaf(x0, wv[i].x, wv[i].w)));
          v = fmaxf(v, 0.0f);
          f16 vh = (f16)v;
          ah[i] = vh;
          al[i] = (f16)((v - (float)vh) * 2048.0f);
        }
        const uint32_t off = ((uint32_t)r << 9) + (hbyte ^ (((uint32_t)(r & 31)) << 4));
        *(f16x8*)(lds + AH_OFF + off) = ah;
        *(f16x8*)(lds + AL_OFF + off) = al;
      }
    }
    __syncthreads();

    // ---- phase C: 3-pass compensated f16 MFMA ----
    f32x16 acc[4];
#pragma unroll
    for (int mt = 0; mt < 4; ++mt)
#pragma unroll
      for (int i = 0; i < 16; ++i) acc[mt][i] = 0.0f;

    // correction passes: acc = Al*Bh + Ah*Bl   (in 2^11-scaled units)
#pragma unroll
    for (int ks = 0; ks < 16; ++ks) {
      const uint32_t kb = (((uint32_t)ks << 5) | koffb) ^ aswz;
      f16x8 fa_l[4], fa_h[4];
#pragma unroll
      for (int mt = 0; mt < 4; ++mt) {
        const uint32_t off = ((uint32_t)mt << 14) + ((uint32_t)arow << 9) + kb;
        fa_l[mt] = *(const f16x8*)(lds + AL_OFF + off);
        fa_h[mt] = *(const f16x8*)(lds + AH_OFF + off);
      }
#pragma unroll
      for (int mt = 0; mt < 4; ++mt)
        acc[mt] = __builtin_amdgcn_mfma_f32_32x32x16_f16(fa_l[mt], Bh[ks], acc[mt], 0,0,0);
#pragma unroll
      for (int mt = 0; mt < 4; ++mt)
        acc[mt] = __builtin_amdgcn_mfma_f32_32x32x16_f16(fa_h[mt], Bl[ks], acc[mt], 0,0,0);
    }
    // undo lo scaling, then main pass: acc += Ah*Bh
#pragma unroll
    for (int mt = 0; mt < 4; ++mt)
#pragma unroll
      for (int i = 0; i < 16; ++i) acc[mt][i] *= 4.8828125e-4f;  // 2^-11
#pragma unroll
    for (int ks = 0; ks < 16; ++ks) {
      const uint32_t kb = (((uint32_t)ks << 5) | koffb) ^ aswz;
      f16x8 fa_h[4];
#pragma unroll
      for (int mt = 0; mt < 4; ++mt) {
        const uint32_t off = ((uint32_t)mt << 14) + ((uint32_t)arow << 9) + kb;
        fa_h[mt] = *(const f16x8*)(lds + AH_OFF + off);
      }
#pragma unroll
      for (int mt = 0; mt < 4; ++mt)
        acc[mt] = __builtin_amdgcn_mfma_f32_32x32x16_f16(fa_h[mt], Bh[ks], acc[mt], 0,0,0);
    }
    __syncthreads();  // all A reads done before aliasing writes

    // ---- phase D: h2 = relu(acc + b2) -> LDS (aliases A buffers) ----
    {
      const float bias = b2s[nb + arow];
      const uint32_t cb = (uint32_t)(nb + arow) << 2;
      const int rb = (lane >> 5) << 2;
#pragma unroll
      for (int mt = 0; mt < 4; ++mt) {
#pragma unroll
        for (int i = 0; i < 16; ++i) {
          const int row = mt*32 + (i & 3) + ((i >> 2) << 3) + rb;
          const float v = fmaxf(acc[mt][i] + bias, 0.0f);
          const uint32_t off = ((uint32_t)row << 10) + (cb ^ (((uint32_t)(row & 31)) << 4));
          *(float*)(lds + H2_OFF + off) = v;
        }
      }
    }
    __syncthreads();

    // ---- phase E: logitC = h2 @ w3^T + b3; parity epilogue; store ----
    {
      const int r = tid >> 2, q = tid & 3;       // 4 lanes cooperate per row
      const uint32_t rswz  = ((uint32_t)(r & 31)) << 4;
      const uint32_t rbase = (uint32_t)r << 10;
      float s0 = 0.f, s1 = 0.f, s2 = 0.f;
#pragma unroll
      for (int ib = 0; ib < 16; ++ib) {
        const int n0 = (q << 6) + (ib << 2);
        const uint32_t cb = (uint32_t)n0 << 2;
        const float4 hv  = *(const float4*)(lds + H2_OFF + (rbase + (cb ^ rswz)));
        const float4 wc0 = *(const float4*)(w3s + n0);
        const float4 wc1 = *(const float4*)(w3s + 256 + n0);
        const float4 wc2 = *(const float4*)(w3s + 512 + n0);
        s0 = fmaf(hv.x, wc0.x, fmaf(hv.y, wc0.y, fmaf(hv.z, wc0.z, fmaf(hv.w, wc0.w, s0))));
        s1 = fmaf(hv.x, wc1.x, fmaf(hv.y, wc1.y, fmaf(hv.z, wc1.z, fmaf(hv.w, wc1.w, s1))));
        s2 = fmaf(hv.x, wc2.x, fmaf(hv.y, wc2.y, fmaf(hv.z, wc2.z, fmaf(hv.w, wc2.w, s2))));
      }
      s0 += __shfl_xor(s0, 1); s1 += __shfl_xor(s1, 1); s2 += __shfl_xor(s2, 1);
      s0 += __shfl_xor(s0, 2); s1 += __shfl_xor(s1, 2); s2 += __shfl_xor(s2, 2);
      const float l0 = s0 + b3s[0];
      const float l1 = s1 + b3s[1];
      const float l2 = s2 + b3s[2];
      const size_t grow = base + (size_t)r;
      if (q == 0) {
        // P(parity odd) = (1 - t0*t1*t2)/2, t = (p_neg - p_pos) = (1-2*sig)/(1+2*eps)
        const float inv1p2e = 1.0f / (1.0f + 2.0f * 1e-5f);
        const float t0 = (1.0f - 2.0f / (1.0f + expf(-l0))) * inv1p2e;
        const float t1 = (1.0f - 2.0f / (1.0f + expf(-l1))) * inv1p2e;
        const float t2 = (1.0f - 2.0f / (1.0f + expf(-l2))) * inv1p2e;
        const float pred1 = 0.5f * (1.0f - t0 * t1 * t2);
        float2 ov;
        ov.x = (1.0f - pred1 + 0.001f) * (1.0f / 1.002f);
        ov.y = (pred1 + 0.001f) * (1.0f / 1.002f);
        *(float2*)(out + grow * 2) = ov;
      } else if (q == 1) {
        out[outL + grow*3 + 0] = l0;
      } else if (q == 2) {
        out[outL + grow*3 + 1] = l1;
      } else {
        out[outL + grow*3 + 2] = l2;
      }
    }
    // next iteration's phase-A barrier fences E's LDS reads vs B's writes
  }
}

extern "C" void kernel_launch(void* const* d_in, const int* in_sizes, int n_in,
                              void* d_out, int out_size, void* d_ws, size_t ws_size,
                              hipStream_t stream) {
  const float* x  = (const float*)d_in[0];
  const float* w1 = (const float*)d_in[1];
  const float* b1 = (const float*)d_in[2];
  const float* w2 = (const float*)d_in[3];
  const float* b2 = (const float*)d_in[4];
  const float* w3 = (const float*)d_in[5];
  const float* b3 = (const float*)d_in[6];
  float* out = (float*)d_out;
  const int Bsz = in_sizes[0] / 3;   // x is (B,3)

  dim3 grid(NBLK), block(THREADS);
  fused_mlp_parity<<<grid, block, 0, stream>>>(x, w1, b1, w2, b2, w3, b3, out, Bsz);
}

// Round 3
// 433.594 us; speedup vs baseline: 4.3898x; 4.3898x over previous
//
#include <hip/hip_runtime.h>

typedef _Float16 f16;
typedef _Float16 f16x8 __attribute__((ext_vector_type(8)));
typedef float f32x16 __attribute__((ext_vector_type(16)));
typedef unsigned long long u64;
typedef unsigned long long u64x2 __attribute__((ext_vector_type(2)));
typedef unsigned int u32;
typedef unsigned int u32x4 __attribute__((ext_vector_type(4)));

#define THREADS 512
#define MTILE   128
#define NBLK    256

// LDS layout (bytes)
#define H1_OFF   0        // f16 [128][256], row stride 512 B, 8B XOR key (row&15)<<3
#define XS_OFF   65536    // f32 [128*3]
#define W1P_OFF  67072    // float4-equiv [256] {w1[h][0..2], b1[h]}, XOR key ((h>>3)&15)<<3
#define PART_OFF 71168    // f32 [4 colwave][128 row][3 c] = 6144
#define LDS_BYTES 77312

__global__ __launch_bounds__(THREADS)
void fused_mlp_parity(const float* __restrict__ x,
                      const float* __restrict__ w1,
                      const float* __restrict__ b1,
                      const float* __restrict__ w2,
                      const float* __restrict__ b2,
                      const float* __restrict__ w3,
                      const float* __restrict__ b3,
                      float* __restrict__ out, int Bsz) {
  __shared__ __align__(128) unsigned char lds[LDS_BYTES];
  const int tid  = threadIdx.x;
  const int lane = tid & 63;
  const int wave = tid >> 6;
  const int arow = lane & 31;
  const int half = lane >> 5;       // k-half for MFMA fragments
  const int cw   = wave & 3;        // col-wave index (4): owns 64 cols of h2
  const int rw   = wave >> 2;       // row-wave index (2): owns 64 rows
  const int mhalf  = cw * 64;
  const int rowblk = rw * 64;

  float* xs   = (float*)(lds + XS_OFF);
  float* part = (float*)(lds + PART_OFF);

  // ---- one-time staging: w1+b1 packed, XOR-swizzled (8-B granularity) ----
  for (int i = tid; i < 256; i += THREADS) {
    float2 lo; lo.x = w1[i*3+0]; lo.y = w1[i*3+1];
    float2 hi; hi.x = w1[i*3+2]; hi.y = b1[i];
    const u32 key = ((u32)(i >> 3) & 15) << 3;
    *(float2*)(lds + W1P_OFF + (((u32)i*16)     ^ key)) = lo;
    *(float2*)(lds + W1P_OFF + (((u32)i*16 + 8) ^ key)) = hi;
  }

  // ---- register-resident operands (loop-invariant) ----
  // A-operand for layer2: w2[col][k], col = mhalf + mt*32 + arow, k = 16ks + 8*half + j
  f16x8 w2A[2][16];
#pragma unroll
  for (int mt = 0; mt < 2; ++mt) {
    const int col = mhalf + mt*32 + arow;
#pragma unroll
    for (int ks = 0; ks < 16; ++ks) {
      const float* src = w2 + (size_t)col*256 + ks*16 + half*8;
      float4 u0 = *(const float4*)src;
      float4 u1 = *(const float4*)(src + 4);
      f16x8 v;
      v[0]=(f16)u0.x; v[1]=(f16)u0.y; v[2]=(f16)u0.z; v[3]=(f16)u0.w;
      v[4]=(f16)u1.x; v[5]=(f16)u1.y; v[6]=(f16)u1.z; v[7]=(f16)u1.w;
      w2A[mt][ks] = v;
    }
  }
  // bias-MFMA operands: acc += b2A * ones puts b2[col] into every row
  f16x8 b2A[2];
#pragma unroll
  for (int mt = 0; mt < 2; ++mt) {
    f16x8 v = {};
    if (half == 0) v[0] = (f16)b2[mhalf + mt*32 + arow];
    b2A[mt] = v;
  }
  f16x8 ones = {};
  if (half == 0) ones[0] = (f16)1.0f;
  // layer-3 A-operand: w3[c][col], c = arow (only 0..2 nonzero), col = mhalf + 16q + 8*half + j
  f16x8 w3A[4];
#pragma unroll
  for (int q = 0; q < 4; ++q) {
    f16x8 v = {};
    if (arow < 3) {
#pragma unroll
      for (int j = 0; j < 8; ++j)
        v[j] = (f16)w3[arow*256 + mhalf + q*16 + half*8 + j];
    }
    w3A[q] = v;
  }
  const float b3r0 = b3[0], b3r1 = b3[1], b3r2 = b3[2];

  const int ntiles = Bsz / MTILE;
  const size_t outL = (size_t)Bsz * 2;

  for (int tile = blockIdx.x; tile < ntiles; tile += gridDim.x) {
    const size_t base = (size_t)tile * MTILE;

    // ---- stage x tile ----
    if (tid < MTILE*3) xs[tid] = x[base*3 + tid];
    __syncthreads();

    // ---- phase B: h1 = relu(x@w1^T + b1) in f32, store f16 to LDS (swizzled) ----
    {
      const int hb = tid & 31;       // col-block: h = hb*8 + i
      const int rg = tid >> 5;       // 16 row-groups of 8 rows
      float4 wv[8];
#pragma unroll
      for (int i = 0; i < 8; ++i) {
        const int h = hb*8 + i;
        const u32 key = ((u32)hb & 15) << 3;
        float2 a = *(const float2*)(lds + W1P_OFF + (((u32)h*16)     ^ key));
        float2 b = *(const float2*)(lds + W1P_OFF + (((u32)h*16 + 8) ^ key));
        wv[i].x = a.x; wv[i].y = a.y; wv[i].z = b.x; wv[i].w = b.y;
      }
#pragma unroll
      for (int rr = 0; rr < 8; ++rr) {
        const int r = rg*8 + rr;
        const float x0 = xs[r*3+0], x1 = xs[r*3+1], x2 = xs[r*3+2];
        f16x8 ah;
#pragma unroll
        for (int i = 0; i < 8; ++i) {
          float v = fmaf(x2, wv[i].z, fmaf(x1, wv[i].y, fmaf(x0, wv[i].x, wv[i].w)));
          ah[i] = (f16)fmaxf(v, 0.0f);
        }
        const u32 rkey = ((u32)(r & 15)) << 3;
        u64x2 packed = __builtin_bit_cast(u64x2, ah);
        *(u64*)(lds + H1_OFF + (u32)r*512 + ((((u32)hb*16)    ) ^ rkey)) = packed[0];
        *(u64*)(lds + H1_OFF + (u32)r*512 + ((((u32)hb*16) + 8) ^ rkey)) = packed[1];
      }
    }
    __syncthreads();

    // ---- phase C: h2^T = w2 · h1^T via MFMA (A=w2 regs, B=h1 from LDS) ----
    f32x16 acc[2][2];
#pragma unroll
    for (int mt = 0; mt < 2; ++mt)
#pragma unroll
      for (int nt = 0; nt < 2; ++nt) {
        f32x16 z = {};
        acc[mt][nt] = __builtin_amdgcn_mfma_f32_32x32x16_f16(b2A[mt], ones, z, 0,0,0);
      }
    const u32 rk = ((u32)(arow & 15)) << 3;
    const u32 half16 = (u32)half * 16;
#pragma unroll
    for (int ks = 0; ks < 16; ++ks) {
#pragma unroll
      for (int nt = 0; nt < 2; ++nt) {
        const unsigned char* rowp = lds + H1_OFF + (u32)(rowblk + nt*32 + arow)*512;
        u64x2 d;
        d[0] = *(const u64*)(rowp + ((((u32)ks*32) + half16    ) ^ rk));
        d[1] = *(const u64*)(rowp + ((((u32)ks*32) + half16 + 8) ^ rk));
        f16x8 frag = __builtin_bit_cast(f16x8, d);
#pragma unroll
        for (int mt = 0; mt < 2; ++mt)
          acc[mt][nt] = __builtin_amdgcn_mfma_f32_32x32x16_f16(w2A[mt][ks], frag, acc[mt][nt], 0,0,0);
      }
    }

    // ---- phase E: relu + pack to f16 + permlane repack + w3-MFMA + partial dump ----
#pragma unroll
    for (int nt = 0; nt < 2; ++nt) {
      f32x16 acc3 = {};
#pragma unroll
      for (int q = 0; q < 4; ++q) {
        const int mt = q >> 1, i0 = (q & 1) * 8;
        const float a0 = fmaxf(acc[mt][nt][i0+0], 0.f);
        const float a1 = fmaxf(acc[mt][nt][i0+1], 0.f);
        const float a2 = fmaxf(acc[mt][nt][i0+2], 0.f);
        const float a3 = fmaxf(acc[mt][nt][i0+3], 0.f);
        const float a4 = fmaxf(acc[mt][nt][i0+4], 0.f);
        const float a5 = fmaxf(acc[mt][nt][i0+5], 0.f);
        const float a6 = fmaxf(acc[mt][nt][i0+6], 0.f);
        const float a7 = fmaxf(acc[mt][nt][i0+7], 0.f);
        u32 P = __builtin_bit_cast(u32, __builtin_amdgcn_cvt_pkrtz(a0, a1));
        u32 Q = __builtin_bit_cast(u32, __builtin_amdgcn_cvt_pkrtz(a2, a3));
        u32 R = __builtin_bit_cast(u32, __builtin_amdgcn_cvt_pkrtz(a4, a5));
        u32 S = __builtin_bit_cast(u32, __builtin_amdgcn_cvt_pkrtz(a6, a7));
        // swap row-halves: after, P = {P.lo, R.lo}, R = {P.hi, R.hi}
        asm("v_permlane32_swap_b32 %0, %1" : "+v"(P), "+v"(R));
        asm("v_permlane32_swap_b32 %0, %1" : "+v"(Q), "+v"(S));
        u32x4 fr; fr[0] = P; fr[1] = Q; fr[2] = R; fr[3] = S;
        f16x8 frag = __builtin_bit_cast(f16x8, fr);
        acc3 = __builtin_amdgcn_mfma_f32_32x32x16_f16(w3A[q], frag, acc3, 0,0,0);
      }
      if (half == 0) {
        // lane holds logit partials c=0,1,2 (regs 0..2) for row = rowblk + nt*32 + arow
        float* pr = part + ((u32)(cw*128 + rowblk + nt*32 + arow))*3;
        pr[0] = acc3[0]; pr[1] = acc3[1]; pr[2] = acc3[2];
      }
    }
    __syncthreads();

    // ---- final epilogue: sum partials, parity math, store ----
    if (tid < MTILE) {
      const int r = tid;
      float l0 = b3r0, l1 = b3r1, l2 = b3r2;
#pragma unroll
      for (int c4 = 0; c4 < 4; ++c4) {
        const float* pr = part + ((u32)(c4*128 + r))*3;
        l0 += pr[0]; l1 += pr[1]; l2 += pr[2];
      }
      const float inv1p2e = 1.0f / (1.0f + 2.0f * 1e-5f);
      const float t0 = (1.0f - 2.0f / (1.0f + __expf(-l0))) * inv1p2e;
      const float t1 = (1.0f - 2.0f / (1.0f + __expf(-l1))) * inv1p2e;
      const float t2 = (1.0f - 2.0f / (1.0f + __expf(-l2))) * inv1p2e;
      const float pred1 = 0.5f * (1.0f - t0 * t1 * t2);
      const size_t grow = base + (size_t)r;
      float2 ov;
      ov.x = (1.0f - pred1 + 0.001f) * (1.0f / 1.002f);
      ov.y = (pred1 + 0.001f) * (1.0f / 1.002f);
      *(float2*)(out + grow*2) = ov;
      out[outL + grow*3 + 0] = l0;
      out[outL + grow*3 + 1] = l1;
      out[outL + grow*3 + 2] = l2;
    }
    // no extra barrier needed: next tile's stage-x + its barrier fences everything
  }
}

extern "C" void kernel_launch(void* const* d_in, const int* in_sizes, int n_in,
                              void* d_out, int out_size, void* d_ws, size_t ws_size,
                              hipStream_t stream) {
  const float* x  = (const float*)d_in[0];
  const float* w1 = (const float*)d_in[1];
  const float* b1 = (const float*)d_in[2];
  const float* w2 = (const float*)d_in[3];
  const float* b2 = (const float*)d_in[4];
  const float* w3 = (const float*)d_in[5];
  const float* b3 = (const float*)d_in[6];
  float* out = (float*)d_out;
  const int Bsz = in_sizes[0] / 3;

  dim3 grid(NBLK), block(THREADS);
  fused_mlp_parity<<<grid, block, 0, stream>>>(x, w1, b1, w2, b2, w3, b3, out, Bsz);
}

// Round 4
// 228.669 us; speedup vs baseline: 8.3238x; 1.8962x over previous
//
#include <hip/hip_runtime.h>

typedef _Float16 f16;
typedef _Float16 f16x8 __attribute__((ext_vector_type(8)));
typedef float f32x16 __attribute__((ext_vector_type(16)));
typedef unsigned int u32;
typedef unsigned int u32x4 __attribute__((ext_vector_type(4)));

#define THREADS 512
#define MTILE   128
#define NBLK    256

// LDS layout (bytes)
#define H1_OFF   0        // f16 [128][256], row stride 512 B, 16B XOR key (row&15)<<4
#define XS_OFF   65536    // f32 [32*128*3] = 49152 B (whole block x chunk)
#define W1P_OFF  114688   // packed w1+b1 [256]*16B, 8B XOR key ((h>>3)&15)<<3
#define PART_OFF 118784   // f32 [8 wave][128 row][3 c] = 12288
#define LDS_BYTES 131072

__global__ __launch_bounds__(THREADS, 1)
void fused_mlp_parity(const float* __restrict__ x,
                      const float* __restrict__ w1,
                      const float* __restrict__ b1,
                      const float* __restrict__ w2,
                      const float* __restrict__ b2,
                      const float* __restrict__ w3,
                      const float* __restrict__ b3,
                      float* __restrict__ out, int Bsz) {
  __shared__ __align__(128) unsigned char lds[LDS_BYTES];
  const int tid  = threadIdx.x;
  const int lane = tid & 63;
  const int wave = tid >> 6;
  const int arow = lane & 31;
  const int half = lane >> 5;

  float* part = (float*)(lds + PART_OFF);

  const int ntiles = Bsz / MTILE;
  const int tpb    = ntiles / NBLK;          // 32 for B=1M
  const int t0     = blockIdx.x * tpb;

  // ---- stage whole x chunk for this block's tiles (coalesced float4) ----
  {
    const float4* xg = (const float4*)(x + (size_t)t0 * (MTILE*3));
    float4* xv = (float4*)(lds + XS_OFF);
    const int n4 = tpb * (MTILE*3/4);        // 3072
    for (int i = tid; i < n4; i += THREADS) xv[i] = xg[i];
  }
  // ---- w1+b1 packed, 8B XOR swizzle (conflict-free phase-B reads) ----
  for (int i = tid; i < 256; i += THREADS) {
    float2 lo; lo.x = w1[i*3+0]; lo.y = w1[i*3+1];
    float2 hi; hi.x = w1[i*3+2]; hi.y = b1[i];
    const u32 key = ((u32)(i >> 3) & 15) << 3;
    *(float2*)(lds + W1P_OFF + (((u32)i*16)     ^ key)) = lo;
    *(float2*)(lds + W1P_OFF + (((u32)i*16 + 8) ^ key)) = hi;
  }

  // ---- register-resident operands: one h2-col per lane (32 cols/wave) ----
  f16x8 w2A[16];
  {
    const int col = (wave << 5) + arow;
#pragma unroll
    for (int ks = 0; ks < 16; ++ks) {
      const float* src = w2 + (size_t)col*256 + ks*16 + half*8;
      float4 u0 = *(const float4*)src;
      float4 u1 = *(const float4*)(src + 4);
      f16x8 v;
      v[0]=(f16)u0.x; v[1]=(f16)u0.y; v[2]=(f16)u0.z; v[3]=(f16)u0.w;
      v[4]=(f16)u1.x; v[5]=(f16)u1.y; v[6]=(f16)u1.z; v[7]=(f16)u1.w;
      w2A[ks] = v;
    }
  }
  f16x8 b2A = {};  if (half == 0) b2A[0] = (f16)b2[(wave<<5) + arow];
  f16x8 ones = {}; if (half == 0) ones[0] = (f16)1.0f;
  f16x8 w3A[2];
#pragma unroll
  for (int q = 0; q < 2; ++q) {
    f16x8 v = {};
    if (arow < 3) {
#pragma unroll
      for (int j = 0; j < 8; ++j)
        v[j] = (f16)w3[arow*256 + (wave<<5) + q*16 + half*8 + j];
    }
    w3A[q] = v;
  }
  const float b3r0 = b3[0], b3r1 = b3[1], b3r2 = b3[2];
  const size_t outL = (size_t)Bsz * 2;

  __syncthreads();

  for (int tl = 0; tl < tpb; ++tl) {
    const size_t base = ((size_t)t0 + tl) * MTILE;

    // ---- phase B: h1 = relu(x@w1^T + b1) fp32 -> f16, b128 store, 16B swizzle ----
    {
      const int hb = tid & 31;             // 8-col block
      const int rg = tid >> 5;             // 16 row-groups of 8 rows
      const float* xs = (const float*)(lds + XS_OFF) + (u32)tl * (MTILE*3);
      const u32 wk = ((u32)hb & 15) << 3;
      float4 wv[8];
#pragma unroll
      for (int i = 0; i < 8; ++i) {
        const int h = hb*8 + i;
        float2 a = *(const float2*)(lds + W1P_OFF + (((u32)h*16)     ^ wk));
        float2 b = *(const float2*)(lds + W1P_OFF + (((u32)h*16 + 8) ^ wk));
        wv[i].x = a.x; wv[i].y = a.y; wv[i].z = b.x; wv[i].w = b.y;
      }
#pragma unroll
      for (int rr = 0; rr < 8; ++rr) {
        const int r = rg*8 + rr;
        const float x0 = xs[r*3+0], x1 = xs[r*3+1], x2 = xs[r*3+2];
        f16x8 ah;
#pragma unroll
        for (int i = 0; i < 8; ++i) {
          float v = fmaf(x2, wv[i].z, fmaf(x1, wv[i].y, fmaf(x0, wv[i].x, wv[i].w)));
          ah[i] = (f16)fmaxf(v, 0.0f);
        }
        *(f16x8*)(lds + H1_OFF + ((u32)r << 9)
                  + ((((u32)hb) << 4) ^ ((((u32)r) & 15) << 4))) = ah;
      }
    }
    __syncthreads();

    // ---- phase C: h2^T = w2·h1^T, A=w2 regs, B=h1 b128 reads (conflict-free) ----
    f32x16 acc[4];
#pragma unroll
    for (int nt = 0; nt < 4; ++nt) {
      f32x16 z = {};
      acc[nt] = __builtin_amdgcn_mfma_f32_32x32x16_f16(b2A, ones, z, 0,0,0);
    }
    {
      const u32 rk = ((u32)(arow & 15)) << 4;
      const u32 cb = (u32)half << 4;
#pragma unroll
      for (int ks = 0; ks < 16; ++ks) {
        f16x8 fr[4];
#pragma unroll
        for (int nt = 0; nt < 4; ++nt)
          fr[nt] = *(const f16x8*)(lds + H1_OFF + ((u32)(nt*32 + arow) << 9)
                                   + (((((u32)ks) << 5) + cb) ^ rk));
#pragma unroll
        for (int nt = 0; nt < 4; ++nt)
          acc[nt] = __builtin_amdgcn_mfma_f32_32x32x16_f16(w2A[ks], fr[nt], acc[nt], 0,0,0);
      }
    }

    // ---- phase E: relu + pkrtz + permlane repack + w3-MFMA + partial dump ----
#pragma unroll
    for (int nt = 0; nt < 4; ++nt) {
      f32x16 a3 = {};
#pragma unroll
      for (int q = 0; q < 2; ++q) {
        const int i0 = q*8;
        const float c0 = fmaxf(acc[nt][i0+0], 0.f), c1 = fmaxf(acc[nt][i0+1], 0.f);
        const float c2 = fmaxf(acc[nt][i0+2], 0.f), c3 = fmaxf(acc[nt][i0+3], 0.f);
        const float c4 = fmaxf(acc[nt][i0+4], 0.f), c5 = fmaxf(acc[nt][i0+5], 0.f);
        const float c6 = fmaxf(acc[nt][i0+6], 0.f), c7 = fmaxf(acc[nt][i0+7], 0.f);
        u32 P = __builtin_bit_cast(u32, __builtin_amdgcn_cvt_pkrtz(c0, c1));
        u32 Q = __builtin_bit_cast(u32, __builtin_amdgcn_cvt_pkrtz(c2, c3));
        u32 R = __builtin_bit_cast(u32, __builtin_amdgcn_cvt_pkrtz(c4, c5));
        u32 S = __builtin_bit_cast(u32, __builtin_amdgcn_cvt_pkrtz(c6, c7));
        asm("v_permlane32_swap_b32 %0, %1" : "+v"(P), "+v"(R));
        asm("v_permlane32_swap_b32 %0, %1" : "+v"(Q), "+v"(S));
        u32x4 w; w[0]=P; w[1]=Q; w[2]=R; w[3]=S;
        a3 = __builtin_amdgcn_mfma_f32_32x32x16_f16(w3A[q], __builtin_bit_cast(f16x8, w), a3, 0,0,0);
      }
      if (half == 0) {
        float* pr = part + (u32)wave*384 + (u32)(nt*32 + arow)*3;
        pr[0] = a3[0]; pr[1] = a3[1]; pr[2] = a3[2];
      }
    }
    __syncthreads();

    // ---- epilogue: sum 8 wave-partials, parity math, store ----
    if (tid < MTILE) {
      const int r = tid;
      float l0 = b3r0, l1 = b3r1, l2 = b3r2;
#pragma unroll
      for (int w8 = 0; w8 < 8; ++w8) {
        const float* pr = part + (u32)w8*384 + (u32)r*3;
        l0 += pr[0]; l1 += pr[1]; l2 += pr[2];
      }
      const float inv1p2e = 1.0f / (1.0f + 2.0f * 1e-5f);
      const float tt0 = (1.0f - 2.0f / (1.0f + __expf(-l0))) * inv1p2e;
      const float tt1 = (1.0f - 2.0f / (1.0f + __expf(-l1))) * inv1p2e;
      const float tt2 = (1.0f - 2.0f / (1.0f + __expf(-l2))) * inv1p2e;
      const float pred1 = 0.5f * (1.0f - tt0 * tt1 * tt2);
      const size_t grow = base + (size_t)r;
      float2 ov;
      ov.x = (1.0f - pred1 + 0.001f) * (1.0f / 1.002f);
      ov.y = (pred1 + 0.001f) * (1.0f / 1.002f);
      *(float2*)(out + grow*2) = ov;
      out[outL + grow*3 + 0] = l0;
      out[outL + grow*3 + 1] = l1;
      out[outL + grow*3 + 2] = l2;
    }
    // next tile's post-B barrier fences epilogue part-reads vs next E-writes
  }
}

extern "C" void kernel_launch(void* const* d_in, const int* in_sizes, int n_in,
                              void* d_out, int out_size, void* d_ws, size_t ws_size,
                              hipStream_t stream) {
  const float* x  = (const float*)d_in[0];
  const float* w1 = (const float*)d_in[1];
  const float* b1 = (const float*)d_in[2];
  const float* w2 = (const float*)d_in[3];
  const float* b2 = (const float*)d_in[4];
  const float* w3 = (const float*)d_in[5];
  const float* b3 = (const float*)d_in[6];
  float* out = (float*)d_out;
  const int Bsz = in_sizes[0] / 3;

  dim3 grid(NBLK), block(THREADS);
  fused_mlp_parity<<<grid, block, 0, stream>>>(x, w1, b1, w2, b2, w3, b3, out, Bsz);
}